// Round 11
// baseline (727.246 us; speedup 1.0000x reference)
//
#include <hip/hip_runtime.h>
#include <hip/hip_bf16.h>
#include <hip/hip_cooperative_groups.h>
#include <math.h>

namespace cg = cooperative_groups;

// Problem constants
#define NN   3000
#define EE   96000
#define BB   64
#define CIN  8
#define MID  16
#define G1   32
#define G2   8
#define FC1N 512
#define FC2N 128
#define OUTN 10
#define EPSV 1e-5f

#define BC   (BB * CIN)          // 512
#define HROW (NN * MID)          // 48000
#define D0   (G2 * NN)           // 24000

// fp32 param-pack offsets (elements)
#define P_EWRAW 0
#define P_SW    96000
#define P_SB    96128
#define P_LNG   96144
#define P_LNB   144144
#define P_C1W   192144
#define P_C1B   192656
#define P_BN1G  192688
#define P_BN1B  192720
#define P_BN1M  192752
#define P_BN1V  192784
#define P_C2W   192816
#define P_C2B   193072
#define P_BN2G  193080
#define P_BN2B  193088
#define P_BN2M  193096
#define P_BN2V  193104
#define P_FB1   193112
#define P_BF1G  193624
#define P_BF1B  194136
#define P_BF1M  194648
#define P_BF1V  195160
#define P_FW2   195672
#define P_FB2   261208
#define P_BF2G  261336
#define P_BF2B  261464
#define P_BF2M  261592
#define P_BF2V  261720
#define P_FOW   261848
#define P_FOB   263128
#define P_TOT   263138

// FC1: K padded 24000 -> 24576 = 64 chunks x 384 (12 MFMA steps of 32).
// 8 fg x 64 kc = 512 virtual blocks -> perfect balance on <=512-block grid.
#define KPAD 24576
#define KCH  384
#define NKC  64

__device__ __forceinline__ float b2f(unsigned short u) {
    union { unsigned int i; float f; } c;
    c.i = ((unsigned int)u) << 16;
    return c.f;
}
__device__ __forceinline__ unsigned short f2b_rne(float x) {
    union { float f; unsigned int u; } c; c.f = x;
    unsigned int r = c.u + 0x7FFFu + ((c.u >> 16) & 1u);
    return (unsigned short)(r >> 16);
}

typedef __attribute__((ext_vector_type(8))) short short8;
typedef __attribute__((ext_vector_type(4))) float f32x4;

struct PTab { const void* p[30]; };

struct MegaArgs {
    const void* ei_raw;
    const void* x_raw;
    const void* w1raw;
    PTab tab;
    int* ei32; int* cnt; int* offA; int* cursor;
    int* rcsr; float* wcsr; float* P;
    float* hb; float* statsS; float* statsQ;
    unsigned short* zT;
    float* out1p; float* z1;
    void* outv;
};

// Single cooperative kernel: all 10 former dispatches as grid.sync phases.
__global__ __launch_bounds__(256, 2)
void k_mega(MegaArgs A) {
    cg::grid_group grid = cg::this_grid();
    __shared__ __align__(16) char smem[20768];
    __shared__ int sh2[2];
    const int t  = threadIdx.x;
    const int nb = gridDim.x;
    const int bid = blockIdx.x;

    // ---- local dtype sniffs (block-uniform; no cross-block dependency) ----
    if (t == 0) {
        const int* pw = (const int*)A.ei_raw;
        int any = 0;
        #pragma unroll
        for (int i = 1; i < 32; i += 2) any |= pw[i];
        sh2[0] = (any == 0) ? 1 : 0;
        unsigned int w = ((const unsigned int*)A.tab.p[0])[0];
        sh2[1] = ((w >> 16) == (w & 0xFFFFu)) ? 1 : 0;
    }
    __syncthreads();
    const int is64 = sh2[0], bf = sh2[1];

    // ================= P0: zero cnt, LN sums, zT pad =================
    for (int i = bid * 256 + t; i < NN; i += nb * 256) A.cnt[i] = 0;
    for (int i = bid * 256 + t; i < BB; i += nb * 256) { A.statsS[i] = 0.f; A.statsQ[i] = 0.f; }
    {   // pad rows k in [D0, KPAD): (KPAD-D0)*BB shorts = 18432 uints
        unsigned int* zp = (unsigned int*)(A.zT + (size_t)D0 * BB);
        for (int i = bid * 256 + t; i < (KPAD - D0) * BB / 2; i += nb * 256) zp[i] = 0u;
    }
    // R10 BUGFIX: P1's histogram atomicAdds into cnt MUST NOT race with P0's
    // zeroing done by other blocks — this sync was missing (absmax 0.118).
    grid.sync();
    // ================= P1: ei convert + histogram; param cvt =================
    for (int i = bid * 256 + t; i < 2 * EE; i += nb * 256) {
        int v = is64 ? (int)((const long long*)A.ei_raw)[i] : ((const int*)A.ei_raw)[i];
        A.ei32[i] = v;
        if (i >= EE) atomicAdd(&A.cnt[v], 1);
    }
    {
        const int off[31] = {
            P_EWRAW, P_SW, P_SB, P_LNG, P_LNB, P_C1W, P_C1B, P_BN1G, P_BN1B, P_BN1M,
            P_BN1V, P_C2W, P_C2B, P_BN2G, P_BN2B, P_BN2M, P_BN2V, P_FB1, P_BF1G,
            P_BF1B, P_BF1M, P_BF1V, P_FW2, P_FB2, P_BF2G, P_BF2B, P_BF2M, P_BF2V,
            P_FOW, P_FOB, P_TOT };
        for (int i = bid * 256 + t; i < P_TOT; i += nb * 256) {
            int r = 0;
            #pragma unroll
            for (int j = 1; j < 31; ++j) r += (i >= off[j]) ? 1 : 0;
            int e = i - off[r];
            A.P[i] = bf ? b2f(((const unsigned short*)A.tab.p[r])[e])
                        : ((const float*)A.tab.p[r])[e];
        }
    }
    grid.sync();
    // ================= P2: exclusive scan (block 0; 3000 = 250 x 12) =========
    if (bid == 0) {
        int* tsum = (int*)smem;
        int loc[12];
        int base = t * 12;
        int s = 0;
        #pragma unroll
        for (int j = 0; j < 12; ++j) {
            int c = (base + j < NN) ? A.cnt[base + j] : 0;
            loc[j] = s; s += c;
        }
        tsum[t] = s;
        __syncthreads();
        for (int d = 1; d < 256; d <<= 1) {
            int v = (t >= d) ? tsum[t - d] : 0;
            __syncthreads();
            tsum[t] += v;
            __syncthreads();
        }
        int excl = tsum[t] - s;
        #pragma unroll
        for (int j = 0; j < 12; ++j) {
            if (base + j < NN) {
                int o = excl + loc[j];
                A.offA[base + j] = o;
                A.cursor[base + j] = o;
            }
        }
        if (t == 255) A.offA[NN] = tsum[255];
    }
    grid.sync();
    // ================= P3: scatter (row, sigmoid(w)) =================
    for (int e = bid * 256 + t; e < EE; e += nb * 256) {
        int p = atomicAdd(&A.cursor[A.ei32[EE + e]], 1);
        A.rcsr[p] = A.ei32[e];
        A.wcsr[p] = 1.f / (1.f + expf(-A.P[P_EWRAW + e]));
    }
    grid.sync();
    // ================= P4: agg + SAGE + ReLU + fused LN partial sums ========
    {
        float* aggL = (float*)smem;        // 512
        float* swL  = aggL + BC;           // 128
        float* sbL  = swL + CIN * MID;     // 16
        float* lnS  = sbL + MID;           // 64
        float* lnQ  = lnS + BB;            // 64
        if (t < CIN * MID) swL[t] = A.P[P_SW + t];
        if (t < MID)       sbL[t] = A.P[P_SB + t];
        if (t < BB) { lnS[t] = 0.f; lnQ[t] = 0.f; }
        float accS[4] = {0.f, 0.f, 0.f, 0.f};
        float accQ[4] = {0.f, 0.f, 0.f, 0.f};
        __syncthreads();
        for (int n = bid; n < NN; n += nb) {
            int k0 = A.offA[n], k1 = A.offA[n + 1];
            float a0 = 0.f, a1 = 0.f, b0 = 0.f, b1 = 0.f;
            int k = k0;
            if (bf) {
                const unsigned int* xu = (const unsigned int*)A.x_raw;
                for (; k + 3 < k1; k += 4) {
                    int   r0 = A.rcsr[k],     r1 = A.rcsr[k + 1];
                    int   r2 = A.rcsr[k + 2], r3 = A.rcsr[k + 3];
                    float w0 = A.wcsr[k],     w1 = A.wcsr[k + 1];
                    float w2 = A.wcsr[k + 2], w3 = A.wcsr[k + 3];
                    unsigned int u0 = xu[(size_t)r0 * 256 + t];
                    unsigned int u1 = xu[(size_t)r1 * 256 + t];
                    unsigned int u2 = xu[(size_t)r2 * 256 + t];
                    unsigned int u3 = xu[(size_t)r3 * 256 + t];
                    a0 += b2f((unsigned short)(u0 & 0xFFFFu)) * w0;
                    a1 += b2f((unsigned short)(u0 >> 16))     * w0;
                    b0 += b2f((unsigned short)(u1 & 0xFFFFu)) * w1;
                    b1 += b2f((unsigned short)(u1 >> 16))     * w1;
                    a0 += b2f((unsigned short)(u2 & 0xFFFFu)) * w2;
                    a1 += b2f((unsigned short)(u2 >> 16))     * w2;
                    b0 += b2f((unsigned short)(u3 & 0xFFFFu)) * w3;
                    b1 += b2f((unsigned short)(u3 >> 16))     * w3;
                }
                for (; k < k1; ++k) {
                    int r0 = A.rcsr[k];
                    float w0 = A.wcsr[k];
                    unsigned int u0 = xu[(size_t)r0 * 256 + t];
                    a0 += b2f((unsigned short)(u0 & 0xFFFFu)) * w0;
                    a1 += b2f((unsigned short)(u0 >> 16))     * w0;
                }
            } else {
                const float* x = (const float*)A.x_raw;
                for (; k + 3 < k1; k += 4) {
                    int   r0 = A.rcsr[k],     r1 = A.rcsr[k + 1];
                    int   r2 = A.rcsr[k + 2], r3 = A.rcsr[k + 3];
                    float w0 = A.wcsr[k],     w1 = A.wcsr[k + 1];
                    float w2 = A.wcsr[k + 2], w3 = A.wcsr[k + 3];
                    const float* xp0 = x + (size_t)r0 * BC;
                    const float* xp1 = x + (size_t)r1 * BC;
                    const float* xp2 = x + (size_t)r2 * BC;
                    const float* xp3 = x + (size_t)r3 * BC;
                    a0 += xp0[t] * w0;  a1 += xp0[t + 256] * w0;
                    b0 += xp1[t] * w1;  b1 += xp1[t + 256] * w1;
                    a0 += xp2[t] * w2;  a1 += xp2[t + 256] * w2;
                    b0 += xp3[t] * w3;  b1 += xp3[t + 256] * w3;
                }
                for (; k < k1; ++k) {
                    int r0 = A.rcsr[k];
                    float w0 = A.wcsr[k];
                    const float* xp0 = x + (size_t)r0 * BC;
                    a0 += xp0[t] * w0;
                    a1 += xp0[t + 256] * w0;
                }
            }
            float inv = 1.f / fmaxf((float)(k1 - k0), 1.f);
            __syncthreads();   // previous iteration's aggL readers done
            if (bf) {
                aggL[2 * t]     = (a0 + b0) * inv;
                aggL[2 * t + 1] = (a1 + b1) * inv;
            } else {
                aggL[t]       = (a0 + b0) * inv;
                aggL[t + 256] = (a1 + b1) * inv;
            }
            __syncthreads();
            #pragma unroll
            for (int r4 = 0; r4 < 4; ++r4) {
                int q = t + r4 * 256;
                int b = q >> 4, m = q & 15;
                float v = sbL[m];
                const float* ag = &aggL[b * CIN];
                #pragma unroll
                for (int c = 0; c < CIN; ++c) v += ag[c] * swL[c * MID + m];
                v = fmaxf(v, 0.f);
                A.hb[(size_t)b * HROW + n * MID + m] = v;
                accS[r4] += v;
                accQ[r4] += v * v;
            }
        }
        __syncthreads();
        #pragma unroll
        for (int r4 = 0; r4 < 4; ++r4) {
            int b = (t + r4 * 256) >> 4;
            atomicAdd(&lnS[b], accS[r4]);
            atomicAdd(&lnQ[b], accQ[r4]);
        }
        __syncthreads();
        if (t < BB) {
            atomicAdd(&A.statsS[t], lnS[t]);
            atomicAdd(&A.statsQ[t], lnQ[t]);
        }
    }
    grid.sync();
    // ================= P6: LN apply + conv stack -> zT (packed bf16) ========
    {
        float* hbt = (float*)smem;           // 64*65 = 4160
        float* w1s = hbt + 64 * 65;          // 512
        float* w2s = w1s + G1 * MID;         // 256
        float* c1s = w2s + G2 * G1;          // 32
        float* s1  = c1s + G1;               // 32
        float* t1  = s1 + G1;                // 32
        float* c2s = t1 + G1;                // 8
        float* s2  = c2s + G2;               // 8
        float* t2  = s2 + G2;                // 8
        float* muL = t2 + G2;                // 64
        float* rsL = muL + BB;               // 64
        for (int j = t; j < G1 * MID; j += 256) w1s[j] = A.P[P_C1W + j];
        if (t < G2 * G1) w2s[t] = A.P[P_C2W + t];
        if (t < G1) {
            float s = A.P[P_BN1G + t] / sqrtf(A.P[P_BN1V + t] + EPSV);
            c1s[t] = A.P[P_C1B + t]; s1[t] = s; t1[t] = A.P[P_BN1B + t] - A.P[P_BN1M + t] * s;
        }
        if (t < G2) {
            float s = A.P[P_BN2G + t] / sqrtf(A.P[P_BN2V + t] + EPSV);
            c2s[t] = A.P[P_C2B + t]; s2[t] = s; t2[t] = A.P[P_BN2B + t] - A.P[P_BN2M + t] * s;
        }
        if (t < BB) {
            float mu = A.statsS[t] / (float)HROW;
            float var = A.statsQ[t] / (float)HROW - mu * mu;
            muL[t] = mu;
            rsL[t] = 1.f / sqrtf(var + EPSV);
        }
        for (int vb = bid; vb < NN / 4; vb += nb) {
            int n0 = vb * 4;
            __syncthreads();    // protect hbt from previous iteration readers
            #pragma unroll
            for (int r = 0; r < 4; ++r) {
                int i = r * 256 + t;
                int b = i >> 4, q = i & 15;
                float4 v = *(const float4*)(A.hb + (size_t)b * HROW + n0 * MID + q * 4);
                int ld = b * 65 + q * 4;
                hbt[ld] = v.x; hbt[ld + 1] = v.y; hbt[ld + 2] = v.z; hbt[ld + 3] = v.w;
            }
            __syncthreads();
            int nl = t >> 6, b = t & 63;
            int n = n0 + nl;
            float mu = muL[b], rs = rsL[b];
            float tv[MID];
            #pragma unroll
            for (int m = 0; m < MID; ++m) {
                float g = A.P[P_LNG + n * MID + m], lb = A.P[P_LNB + n * MID + m];
                tv[m] = (hbt[b * 65 + nl * MID + m] - mu) * rs * g + lb;
            }
            float v1[G1];
            #pragma unroll
            for (int o = 0; o < G1; ++o) {
                float d = c1s[o];
                #pragma unroll
                for (int m = 0; m < MID; ++m) d += w1s[o * MID + m] * tv[m];
                d = fmaxf(d, 0.f);
                v1[o] = d * s1[o] + t1[o];
            }
            #pragma unroll
            for (int o2 = 0; o2 < G2; ++o2) {
                float d = c2s[o2];
                #pragma unroll
                for (int c = 0; c < G1; ++c) d += w2s[o2 * G1 + c] * v1[c];
                d = fmaxf(d, 0.f);
                A.zT[((size_t)(o2 * NN + n)) * BB + b] = f2b_rne(d * s2[o2] + t2[o2]);
            }
        }
    }
    grid.sync();
    // ================= P7: FC1 MFMA bf16 (512 virtual blocks) =================
    {
        unsigned int* zs = (unsigned int*)smem;   // 64 x 20 u32 (80-B rows)
        const float*          w1f = (const float*)A.w1raw;
        const unsigned short* w1b = (const unsigned short*)A.w1raw;
        int lane = t & 63;
        int wv = t >> 6;
        int n = lane & 15;
        int q = lane >> 4;
        int zb = t & 63;
        int kg = t >> 6;
        for (int vb = bid; vb < 8 * NKC; vb += nb) {
            int fg = vb & 7, kc = vb >> 3;
            int fbase = fg * 64 + wv * 16;
            const size_t kcb = (size_t)kc * KCH;
            f32x4 acc0 = {0.f, 0.f, 0.f, 0.f};
            f32x4 acc1 = {0.f, 0.f, 0.f, 0.f};
            f32x4 acc2 = {0.f, 0.f, 0.f, 0.f};
            f32x4 acc3 = {0.f, 0.f, 0.f, 0.f};
            for (int ks = 0; ks < KCH / 32; ++ks) {
                size_t k0 = kcb + (size_t)ks * 32;
                const unsigned short* zsrc = A.zT + (k0 + kg * 8) * BB + zb;
                unsigned short zv[8];
                #pragma unroll
                for (int j = 0; j < 8; ++j) zv[j] = zsrc[j * BB];
                unsigned int pk0 = (unsigned int)zv[0] | ((unsigned int)zv[1] << 16);
                unsigned int pk1 = (unsigned int)zv[2] | ((unsigned int)zv[3] << 16);
                unsigned int pk2 = (unsigned int)zv[4] | ((unsigned int)zv[5] << 16);
                unsigned int pk3 = (unsigned int)zv[6] | ((unsigned int)zv[7] << 16);
                __syncthreads();
                *(uint4*)&zs[zb * 20 + kg * 4] = make_uint4(pk0, pk1, pk2, pk3);
                short8 av = {0, 0, 0, 0, 0, 0, 0, 0};
                if (k0 < D0) {   // K-pad guard: D0 % 32 == 0, steps all-in or all-out
                    if (bf) {
                        av = *(const short8*)(w1b + (size_t)(fbase + n) * D0 + k0 + q * 8);
                    } else {
                        const float* wr = w1f + (size_t)(fbase + n) * D0 + k0 + q * 8;
                        float4 wa = *(const float4*)wr;
                        float4 wb = *(const float4*)(wr + 4);
                        av[0] = (short)f2b_rne(wa.x); av[1] = (short)f2b_rne(wa.y);
                        av[2] = (short)f2b_rne(wa.z); av[3] = (short)f2b_rne(wa.w);
                        av[4] = (short)f2b_rne(wb.x); av[5] = (short)f2b_rne(wb.y);
                        av[6] = (short)f2b_rne(wb.z); av[7] = (short)f2b_rne(wb.w);
                    }
                }
                __syncthreads();
                const char* zbase = (const char*)zs + q * 16;
                short8 bv0 = *(const short8*)(zbase + (0  + n) * 80);
                short8 bv1 = *(const short8*)(zbase + (16 + n) * 80);
                short8 bv2 = *(const short8*)(zbase + (32 + n) * 80);
                short8 bv3 = *(const short8*)(zbase + (48 + n) * 80);
                acc0 = __builtin_amdgcn_mfma_f32_16x16x32_bf16(av, bv0, acc0, 0, 0, 0);
                acc1 = __builtin_amdgcn_mfma_f32_16x16x32_bf16(av, bv1, acc1, 0, 0, 0);
                acc2 = __builtin_amdgcn_mfma_f32_16x16x32_bf16(av, bv2, acc2, 0, 0, 0);
                acc3 = __builtin_amdgcn_mfma_f32_16x16x32_bf16(av, bv3, acc3, 0, 0, 0);
            }
            float* op = A.out1p + ((size_t)kc * FC1N + fbase + q * 4) * BB + n;
            #pragma unroll
            for (int r = 0; r < 4; ++r) {
                op[r * BB +  0] = acc0[r];
                op[r * BB + 16] = acc1[r];
                op[r * BB + 32] = acc2[r];
                op[r * BB + 48] = acc3[r];
            }
        }
    }
    grid.sync();
    // ================= P8: FC1 reduce + bias + bn + relu =================
    for (int i = bid * 256 + t; i < BB * FC1N; i += nb * 256) {
        int f = i >> 6, b = i & 63;
        float acc = 0.f;
        for (int kc = 0; kc < NKC; ++kc)
            acc += A.out1p[((size_t)kc * FC1N + f) * BB + b];
        acc += A.P[P_FB1 + f];
        float s = A.P[P_BF1G + f] / sqrtf(A.P[P_BF1V + f] + EPSV);
        acc = (acc - A.P[P_BF1M + f]) * s + A.P[P_BF1B + f];
        A.z1[b * FC1N + f] = fmaxf(acc, 0.f);
    }
    grid.sync();
    // ================= P9: FC2 + bn + relu + head + softmax =================
    if (bid < BB) {
        float* zsrc = (float*)smem;          // 512
        float* z2s  = zsrc + FC1N;           // 128
        float* lg   = z2s + FC2N;            // 10 (+pad)
        float* red  = lg + 12;               // 2
        int b = bid;
        zsrc[t]       = A.z1[b * FC1N + t];
        zsrc[t + 256] = A.z1[b * FC1N + t + 256];
        __syncthreads();
        if (t < FC2N) {
            int f = t;
            const float4* wr = (const float4*)(A.P + P_FW2 + (size_t)f * FC1N);
            const float4* zr = (const float4*)zsrc;
            float acc = A.P[P_FB2 + f];
            for (int k = 0; k < FC1N / 4; ++k) {
                float4 wv = wr[k];
                float4 zv = zr[k];
                acc += wv.x * zv.x + wv.y * zv.y + wv.z * zv.z + wv.w * zv.w;
            }
            float s = A.P[P_BF2G + f] / sqrtf(A.P[P_BF2V + f] + EPSV);
            acc = (acc - A.P[P_BF2M + f]) * s + A.P[P_BF2B + f];
            z2s[f] = fmaxf(acc, 0.f);
        }
        __syncthreads();
        if (t < OUTN) {
            float acc = A.P[P_FOB + t];
            const float* wr = A.P + P_FOW + t * FC2N;
            for (int k = 0; k < FC2N; ++k) acc += wr[k] * z2s[k];
            lg[t] = acc;
        }
        __syncthreads();
        if (t == 0) {
            float mx = lg[0];
            for (int o = 1; o < OUTN; ++o) mx = fmaxf(mx, lg[o]);
            float s = 0.f;
            for (int o = 0; o < OUTN; ++o) s += expf(lg[o] - mx);
            red[0] = mx; red[1] = s;
        }
        __syncthreads();
        if (t < OUTN) {
            float p = expf(lg[t] - red[0]) / red[1];
            if (bf) {
                __hip_bfloat16* o = (__hip_bfloat16*)A.outv;
                o[b * OUTN + t] = __float2bfloat16(p);
                o[BB * OUTN + b * OUTN + t] = __float2bfloat16(lg[t]);
            } else {
                float* o = (float*)A.outv;
                o[b * OUTN + t] = p;
                o[BB * OUTN + b * OUTN + t] = lg[t];
            }
        }
    }
}

// ---------------------------------------------------------------------------
extern "C" void kernel_launch(void* const* d_in, const int* in_sizes, int n_in,
                              void* d_out, int out_size, void* d_ws, size_t ws_size,
                              hipStream_t stream) {
    char* ws = (char*)d_ws;
    size_t o = 0;
    auto carve = [&](size_t bytes) { void* p = ws + o; o += (bytes + 255) & ~(size_t)255; return p; };
    MegaArgs A;
    A.ei32   = (int*)  carve((size_t)2 * EE * sizeof(int));
    A.cnt    = (int*)  carve(NN * sizeof(int));
    A.offA   = (int*)  carve((NN + 1) * sizeof(int));
    A.cursor = (int*)  carve(NN * sizeof(int));
    A.rcsr   = (int*)  carve(EE * sizeof(int));
    A.wcsr   = (float*)carve(EE * sizeof(float));
    A.P      = (float*)carve((size_t)P_TOT * sizeof(float));
    A.hb     = (float*)carve((size_t)BB * HROW * sizeof(float));
    A.statsS = (float*)carve(BB * sizeof(float));
    A.statsQ = (float*)carve(BB * sizeof(float));
    A.zT     = (unsigned short*)carve((size_t)KPAD * BB * sizeof(unsigned short));
    A.out1p  = (float*)carve((size_t)NKC * FC1N * BB * sizeof(float));
    A.z1     = (float*)carve(BB * FC1N * sizeof(float));

    A.ei_raw = d_in[1];
    A.x_raw  = d_in[0];
    A.w1raw  = d_in[20];
    A.outv   = d_out;
    A.tab.p[0]  = d_in[2];   A.tab.p[1]  = d_in[4];   A.tab.p[2]  = d_in[5];
    A.tab.p[3]  = d_in[6];   A.tab.p[4]  = d_in[7];   A.tab.p[5]  = d_in[8];
    A.tab.p[6]  = d_in[9];   A.tab.p[7]  = d_in[10];  A.tab.p[8]  = d_in[11];
    A.tab.p[9]  = d_in[12];  A.tab.p[10] = d_in[13];  A.tab.p[11] = d_in[14];
    A.tab.p[12] = d_in[15];  A.tab.p[13] = d_in[16];  A.tab.p[14] = d_in[17];
    A.tab.p[15] = d_in[18];  A.tab.p[16] = d_in[19];  A.tab.p[17] = d_in[21];
    A.tab.p[18] = d_in[22];  A.tab.p[19] = d_in[23];  A.tab.p[20] = d_in[24];
    A.tab.p[21] = d_in[25];  A.tab.p[22] = d_in[26];  A.tab.p[23] = d_in[27];
    A.tab.p[24] = d_in[28];  A.tab.p[25] = d_in[29];  A.tab.p[26] = d_in[30];
    A.tab.p[27] = d_in[31];  A.tab.p[28] = d_in[32];  A.tab.p[29] = d_in[33];

    // Cooperative grid: co-residency-bounded, <= 512 (phases are grid-agnostic).
    int maxB = 0;
    if (hipOccupancyMaxActiveBlocksPerMultiprocessor(&maxB, k_mega, 256, 0) != hipSuccess
        || maxB < 1) maxB = 1;
    int grid = maxB * 256;
    if (grid > 512) grid = 512;

    void* args[] = { (void*)&A };
    hipLaunchCooperativeKernel((void*)k_mega, dim3(grid), dim3(256), args, 0, stream);
}

// Round 12
// 268.659 us; speedup vs baseline: 2.7070x; 2.7070x over previous
//
#include <hip/hip_runtime.h>
#include <hip/hip_bf16.h>
#include <math.h>

// Problem constants
#define NN   3000
#define EE   96000
#define BB   64
#define CIN  8
#define MID  16
#define G1   32
#define G2   8
#define FC1N 512
#define FC2N 128
#define OUTN 10
#define EPSV 1e-5f

#define BC   (BB * CIN)          // 512
#define HROW (NN * MID)          // 48000
#define D0   (G2 * NN)           // 24000

// fp32 param-pack offsets (elements)
#define P_EWRAW 0
#define P_SW    96000
#define P_SB    96128
#define P_LNG   96144
#define P_LNB   144144
#define P_C1W   192144
#define P_C1B   192656
#define P_BN1G  192688
#define P_BN1B  192720
#define P_BN1M  192752
#define P_BN1V  192784
#define P_C2W   192816
#define P_C2B   193072
#define P_BN2G  193080
#define P_BN2B  193088
#define P_BN2M  193096
#define P_BN2V  193104
#define P_FB1   193112
#define P_BF1G  193624
#define P_BF1B  194136
#define P_BF1M  194648
#define P_BF1V  195160
#define P_FW2   195672
#define P_FB2   261208
#define P_BF2G  261336
#define P_BF2B  261464
#define P_BF2M  261592
#define P_BF2V  261720
#define P_FOW   261848
#define P_FOB   263128
#define P_TOT   263138

// FC1 K-split: 24000 = 75 chunks x 320; each chunk = 10 MFMA K-steps of 32
#define KCH  320
#define NKC  75

__device__ __forceinline__ float b2f(unsigned short u) {
    union { unsigned int i; float f; } c;
    c.i = ((unsigned int)u) << 16;
    return c.f;
}
__device__ __forceinline__ unsigned short f2b_rne(float x) {
    union { float f; unsigned int u; } c; c.f = x;
    unsigned int r = c.u + 0x7FFFu + ((c.u >> 16) & 1u);
    return (unsigned short)(r >> 16);
}

typedef __attribute__((ext_vector_type(8))) short short8;
typedef __attribute__((ext_vector_type(4))) float f32x4;

// ---------------------------------------------------------------------------
// K_prep: fused dtype sniffs + edge_index convert + histogram + param cvt.
struct PTab { const void* p[30]; };
__global__ __launch_bounds__(256)
void k_prep(const void* __restrict__ ei_raw, const unsigned int* __restrict__ ewr,
            PTab tab,
            int* __restrict__ ei32, int* __restrict__ cnt, int* __restrict__ flags,
            float* __restrict__ P) {
    __shared__ int sh_is64, sh_bf;
    if (threadIdx.x == 0) {
        const int* pw = (const int*)ei_raw;
        int any = 0;
        #pragma unroll
        for (int i = 1; i < 32; i += 2) any |= pw[i];
        sh_is64 = (any == 0) ? 1 : 0;
        unsigned int w = ewr[0];
        sh_bf = ((w >> 16) == (w & 0xFFFFu)) ? 1 : 0;
        if (blockIdx.x == 0) flags[0] = sh_bf;
    }
    __syncthreads();
    int bf = sh_bf;
    long long gi = (long long)blockIdx.x * blockDim.x + threadIdx.x;
    if (gi < 2 * EE) {
        int i = (int)gi;
        int v = sh_is64 ? (int)((const long long*)ei_raw)[i]
                        : ((const int*)ei_raw)[i];
        ei32[i] = v;
        if (i >= EE) atomicAdd(&cnt[v], 1);   // col half
        return;
    }
    gi -= 2 * EE;
    if (gi >= P_TOT) return;
    int i = (int)gi;
    const int off[31] = {
        P_EWRAW, P_SW, P_SB, P_LNG, P_LNB, P_C1W, P_C1B, P_BN1G, P_BN1B, P_BN1M,
        P_BN1V, P_C2W, P_C2B, P_BN2G, P_BN2B, P_BN2M, P_BN2V, P_FB1, P_BF1G,
        P_BF1B, P_BF1M, P_BF1V, P_FW2, P_FB2, P_BF2G, P_BF2B, P_BF2M, P_BF2V,
        P_FOW, P_FOB, P_TOT };
    int r = 0;
    #pragma unroll
    for (int j = 1; j < 31; ++j) r += (i >= off[j]) ? 1 : 0;
    int e = i - off[r];
    P[i] = bf ? b2f(((const unsigned short*)tab.p[r])[e])
              : ((const float*)tab.p[r])[e];
}

// K2: single-block exclusive scan over N=3000 counts
__global__ void k_scan(const int* __restrict__ cnt, int* __restrict__ off,
                       int* __restrict__ cursor) {
    __shared__ int part[1024];
    int t = threadIdx.x;
    int base = t * 3;
    int c0 = 0, c1 = 0, c2 = 0;
    if (base     < NN) c0 = cnt[base];
    if (base + 1 < NN) c1 = cnt[base + 1];
    if (base + 2 < NN) c2 = cnt[base + 2];
    int s = c0 + c1 + c2;
    part[t] = s;
    __syncthreads();
    for (int d = 1; d < 1024; d <<= 1) {
        int v = (t >= d) ? part[t - d] : 0;
        __syncthreads();
        part[t] += v;
        __syncthreads();
    }
    int excl = part[t] - s;
    if (base < NN)     { off[base]     = excl;           cursor[base]     = excl; }
    if (base + 1 < NN) { off[base + 1] = excl + c0;      cursor[base + 1] = excl + c0; }
    if (base + 2 < NN) { off[base + 2] = excl + c0 + c1; cursor[base + 2] = excl + c0 + c1; }
    if (t == 1023) off[NN] = part[1023];
}

// K3: scatter (row, sigmoid(w)) into CSR order
__global__ void k_scatter(const int* __restrict__ ei, const float* __restrict__ ew,
                          int* __restrict__ cursor,
                          int* __restrict__ rcsr, float* __restrict__ wcsr) {
    int e = blockIdx.x * blockDim.x + threadIdx.x;
    if (e < EE) {
        int p = atomicAdd(&cursor[ei[EE + e]], 1);
        rcsr[p] = ei[e];
        wcsr[p] = 1.f / (1.f + expf(-ew[e]));
    }
}

// K4: per-node scatter-mean + SAGE matmul + ReLU -> hb[b][n][m], with FUSED
// LayerNorm partial sums (R11: replaces k_ln_stats — saves a dispatch + 12 MB
// hb re-read). Grid = 750 blocks x 4 nodes: keeps 3000 waves of gather TLP
// (the R11 mega lesson) while capping global atomic chains at 750.
__global__ __launch_bounds__(256)
void k_agg_sage(const void* __restrict__ xraw, const int* __restrict__ flags,
                const int* __restrict__ off,
                const int* __restrict__ rcsr, const float* __restrict__ wcsr,
                const float* __restrict__ sw, const float* __restrict__ sb,
                float* __restrict__ hb,
                float* __restrict__ statsS, float* __restrict__ statsQ) {
    __shared__ float aggL[BC];
    __shared__ float swL[CIN * MID];
    __shared__ float sbL[MID];
    __shared__ float lnS[BB], lnQ[BB];
    int t = threadIdx.x;
    if (t < CIN * MID) swL[t] = sw[t];
    if (t < MID)       sbL[t] = sb[t];
    if (t < BB) { lnS[t] = 0.f; lnQ[t] = 0.f; }
    int bf = flags[0];
    float accS[4] = {0.f, 0.f, 0.f, 0.f};
    float accQ[4] = {0.f, 0.f, 0.f, 0.f};
    __syncthreads();
    for (int j = 0; j < 4; ++j) {
        int n = blockIdx.x * 4 + j;
        int k0 = off[n], k1 = off[n + 1];
        float a0 = 0.f, a1 = 0.f, b0 = 0.f, b1 = 0.f;
        int k = k0;
        if (bf) {
            const unsigned int* xu = (const unsigned int*)xraw;   // [n][256]
            for (; k + 3 < k1; k += 4) {
                int   r0 = rcsr[k],     r1 = rcsr[k + 1];
                int   r2 = rcsr[k + 2], r3 = rcsr[k + 3];
                float w0 = wcsr[k],     w1 = wcsr[k + 1];
                float w2 = wcsr[k + 2], w3 = wcsr[k + 3];
                unsigned int u0 = xu[(size_t)r0 * 256 + t];
                unsigned int u1 = xu[(size_t)r1 * 256 + t];
                unsigned int u2 = xu[(size_t)r2 * 256 + t];
                unsigned int u3 = xu[(size_t)r3 * 256 + t];
                a0 += b2f((unsigned short)(u0 & 0xFFFFu)) * w0;
                a1 += b2f((unsigned short)(u0 >> 16))     * w0;
                b0 += b2f((unsigned short)(u1 & 0xFFFFu)) * w1;
                b1 += b2f((unsigned short)(u1 >> 16))     * w1;
                a0 += b2f((unsigned short)(u2 & 0xFFFFu)) * w2;
                a1 += b2f((unsigned short)(u2 >> 16))     * w2;
                b0 += b2f((unsigned short)(u3 & 0xFFFFu)) * w3;
                b1 += b2f((unsigned short)(u3 >> 16))     * w3;
            }
            for (; k < k1; ++k) {
                int r0 = rcsr[k];
                float w0 = wcsr[k];
                unsigned int u0 = xu[(size_t)r0 * 256 + t];
                a0 += b2f((unsigned short)(u0 & 0xFFFFu)) * w0;
                a1 += b2f((unsigned short)(u0 >> 16))     * w0;
            }
        } else {
            const float* x = (const float*)xraw;
            for (; k + 3 < k1; k += 4) {
                int   r0 = rcsr[k],     r1 = rcsr[k + 1];
                int   r2 = rcsr[k + 2], r3 = rcsr[k + 3];
                float w0 = wcsr[k],     w1 = wcsr[k + 1];
                float w2 = wcsr[k + 2], w3 = wcsr[k + 3];
                const float* xp0 = x + (size_t)r0 * BC;
                const float* xp1 = x + (size_t)r1 * BC;
                const float* xp2 = x + (size_t)r2 * BC;
                const float* xp3 = x + (size_t)r3 * BC;
                a0 += xp0[t] * w0;  a1 += xp0[t + 256] * w0;
                b0 += xp1[t] * w1;  b1 += xp1[t + 256] * w1;
                a0 += xp2[t] * w2;  a1 += xp2[t + 256] * w2;
                b0 += xp3[t] * w3;  b1 += xp3[t + 256] * w3;
            }
            for (; k < k1; ++k) {
                int r0 = rcsr[k];
                float w0 = wcsr[k];
                const float* xp0 = x + (size_t)r0 * BC;
                a0 += xp0[t] * w0;
                a1 += xp0[t + 256] * w0;
            }
        }
        float inv = 1.f / fmaxf((float)(k1 - k0), 1.f);
        __syncthreads();   // previous node's aggL readers done
        if (bf) {
            aggL[2 * t]     = (a0 + b0) * inv;
            aggL[2 * t + 1] = (a1 + b1) * inv;
        } else {
            aggL[t]       = (a0 + b0) * inv;
            aggL[t + 256] = (a1 + b1) * inv;
        }
        __syncthreads();
        #pragma unroll
        for (int r4 = 0; r4 < 4; ++r4) {
            int q = t + r4 * 256;
            int b = q >> 4, m = q & 15;
            float v = sbL[m];
            const float* ag = &aggL[b * CIN];
            #pragma unroll
            for (int c = 0; c < CIN; ++c) v += ag[c] * swL[c * MID + m];
            v = fmaxf(v, 0.f);
            hb[(size_t)b * HROW + n * MID + m] = v;
            accS[r4] += v;
            accQ[r4] += v * v;
        }
    }
    // block-level LN reduction, then one global atomic per (b, S/Q)
    __syncthreads();
    #pragma unroll
    for (int r4 = 0; r4 < 4; ++r4) {
        int b = (t + r4 * 256) >> 4;
        atomicAdd(&lnS[b], accS[r4]);
        atomicAdd(&lnQ[b], accQ[r4]);
    }
    __syncthreads();
    if (t < BB) {
        atomicAdd(&statsS[t], lnS[t]);
        atomicAdd(&statsQ[t], lnQ[t]);
    }
}

// K6: LN apply + conv1(+relu+bn1) + conv2(+relu+bn2) -> zT (packed bf16)
__global__ __launch_bounds__(256)
void k_conv_stack(const float* __restrict__ hb,
                  const float* __restrict__ statsS, const float* __restrict__ statsQ,
                  const float* __restrict__ P, unsigned short* __restrict__ zT) {
    __shared__ float hbt[64 * 65];
    __shared__ float w1s[G1 * MID], w2s[G2 * G1];
    __shared__ float c1s[G1], s1[G1], t1[G1];
    __shared__ float c2s[G2], s2[G2], t2[G2];
    int t = threadIdx.x;
    int n0 = blockIdx.x * 4;
    for (int j = t; j < G1 * MID; j += 256) w1s[j] = P[P_C1W + j];  // 512 > 256
    if (t < G2 * G1)  w2s[t] = P[P_C2W + t];
    if (t < G1) {
        float s = P[P_BN1G + t] / sqrtf(P[P_BN1V + t] + EPSV);
        c1s[t] = P[P_C1B + t]; s1[t] = s; t1[t] = P[P_BN1B + t] - P[P_BN1M + t] * s;
    }
    if (t < G2) {
        float s = P[P_BN2G + t] / sqrtf(P[P_BN2V + t] + EPSV);
        c2s[t] = P[P_C2B + t]; s2[t] = s; t2[t] = P[P_BN2B + t] - P[P_BN2M + t] * s;
    }
    #pragma unroll
    for (int r = 0; r < 4; ++r) {
        int i = r * 256 + t;
        int b = i >> 4, q = i & 15;
        float4 v = *(const float4*)(hb + (size_t)b * HROW + n0 * MID + q * 4);
        int ld = b * 65 + q * 4;
        hbt[ld] = v.x; hbt[ld + 1] = v.y; hbt[ld + 2] = v.z; hbt[ld + 3] = v.w;
    }
    __syncthreads();
    int nl = t >> 6, b = t & 63;
    int n = n0 + nl;
    float mu = statsS[b] / (float)HROW;
    float var = statsQ[b] / (float)HROW - mu * mu;
    float rs = 1.f / sqrtf(var + EPSV);
    float tv[MID];
    #pragma unroll
    for (int m = 0; m < MID; ++m) {
        float g = P[P_LNG + n * MID + m], lb = P[P_LNB + n * MID + m];
        tv[m] = (hbt[b * 65 + nl * MID + m] - mu) * rs * g + lb;
    }
    float v1[G1];
    #pragma unroll
    for (int o = 0; o < G1; ++o) {
        float d = c1s[o];
        #pragma unroll
        for (int m = 0; m < MID; ++m) d += w1s[o * MID + m] * tv[m];
        d = fmaxf(d, 0.f);
        v1[o] = d * s1[o] + t1[o];
    }
    #pragma unroll
    for (int o2 = 0; o2 < G2; ++o2) {
        float d = c2s[o2];
        #pragma unroll
        for (int c = 0; c < G1; ++c) d += w2s[o2 * G1 + c] * v1[c];
        d = fmaxf(d, 0.f);
        zT[((size_t)(o2 * NN + n)) * BB + b] = f2b_rne(d * s2[o2] + t2[o2]);
    }
}

// K7: FC1 partial GEMM via MFMA bf16 (R8 design, best measured).
__global__ __launch_bounds__(256)
void k_fc1(const unsigned short* __restrict__ zT, const void* __restrict__ w1raw,
           const int* __restrict__ flags, float* __restrict__ out1p) {
    __shared__ unsigned int zs[64 * 20];   // [b][k-pair], row = 20 u32 = 80 B
    int kc = blockIdx.y;
    int t = threadIdx.x;
    int lane = t & 63;
    int wv = t >> 6;
    int n = lane & 15;           // f-row in A, b-col in B/D
    int q = lane >> 4;           // quad
    int fbase = blockIdx.x * 64 + wv * 16;
    int bf = flags[0];
    const size_t kcb = (size_t)kc * KCH;
    const float*          w1f = (const float*)w1raw;
    const unsigned short* w1b = (const unsigned short*)w1raw;

    f32x4 acc0 = {0.f, 0.f, 0.f, 0.f};
    f32x4 acc1 = {0.f, 0.f, 0.f, 0.f};
    f32x4 acc2 = {0.f, 0.f, 0.f, 0.f};
    f32x4 acc3 = {0.f, 0.f, 0.f, 0.f};

    int zb = t & 63;
    int kg = t >> 6;

    for (int ks = 0; ks < KCH / 32; ++ks) {
        size_t k0 = kcb + (size_t)ks * 32;
        const unsigned short* zsrc = zT + (k0 + kg * 8) * BB + zb;
        unsigned short zv[8];
        #pragma unroll
        for (int j = 0; j < 8; ++j) zv[j] = zsrc[j * BB];
        unsigned int pk0 = (unsigned int)zv[0] | ((unsigned int)zv[1] << 16);
        unsigned int pk1 = (unsigned int)zv[2] | ((unsigned int)zv[3] << 16);
        unsigned int pk2 = (unsigned int)zv[4] | ((unsigned int)zv[5] << 16);
        unsigned int pk3 = (unsigned int)zv[6] | ((unsigned int)zv[7] << 16);
        __syncthreads();
        *(uint4*)&zs[zb * 20 + kg * 4] = make_uint4(pk0, pk1, pk2, pk3);
        short8 av;
        if (bf) {
            av = *(const short8*)(w1b + (size_t)(fbase + n) * D0 + k0 + q * 8);
        } else {
            const float* wr = w1f + (size_t)(fbase + n) * D0 + k0 + q * 8;
            float4 wa = *(const float4*)wr;
            float4 wb = *(const float4*)(wr + 4);
            av[0] = (short)f2b_rne(wa.x); av[1] = (short)f2b_rne(wa.y);
            av[2] = (short)f2b_rne(wa.z); av[3] = (short)f2b_rne(wa.w);
            av[4] = (short)f2b_rne(wb.x); av[5] = (short)f2b_rne(wb.y);
            av[6] = (short)f2b_rne(wb.z); av[7] = (short)f2b_rne(wb.w);
        }
        __syncthreads();
        const char* zbase = (const char*)zs + q * 16;
        short8 bv0 = *(const short8*)(zbase + (0  + n) * 80);
        short8 bv1 = *(const short8*)(zbase + (16 + n) * 80);
        short8 bv2 = *(const short8*)(zbase + (32 + n) * 80);
        short8 bv3 = *(const short8*)(zbase + (48 + n) * 80);
        acc0 = __builtin_amdgcn_mfma_f32_16x16x32_bf16(av, bv0, acc0, 0, 0, 0);
        acc1 = __builtin_amdgcn_mfma_f32_16x16x32_bf16(av, bv1, acc1, 0, 0, 0);
        acc2 = __builtin_amdgcn_mfma_f32_16x16x32_bf16(av, bv2, acc2, 0, 0, 0);
        acc3 = __builtin_amdgcn_mfma_f32_16x16x32_bf16(av, bv3, acc3, 0, 0, 0);
    }
    float* op = out1p + ((size_t)kc * FC1N + fbase + q * 4) * BB + n;
    #pragma unroll
    for (int r = 0; r < 4; ++r) {
        op[r * BB +  0] = acc0[r];
        op[r * BB + 16] = acc1[r];
        op[r * BB + 32] = acc2[r];
        op[r * BB + 48] = acc3[r];
    }
}

// K8: FC1 reduce partials + bias + bn + relu
__global__ void k_fc1_fin(const float* __restrict__ out1p, const float* __restrict__ P,
                          float* __restrict__ z1) {
    int i = blockIdx.x * blockDim.x + threadIdx.x;
    if (i < BB * FC1N) {
        int f = i >> 6, b = i & 63;
        float acc = 0.f;
        for (int kc = 0; kc < NKC; ++kc)
            acc += out1p[((size_t)kc * FC1N + f) * BB + b];
        acc += P[P_FB1 + f];
        float s = P[P_BF1G + f] / sqrtf(P[P_BF1V + f] + EPSV);
        acc = (acc - P[P_BF1M + f]) * s + P[P_BF1B + f];
        z1[b * FC1N + f] = fmaxf(acc, 0.f);
    }
}

// K9: fused FC2(+bn+relu) + head + softmax; one block per batch element.
__global__ __launch_bounds__(128)
void k_fc2head(const float* __restrict__ z1, const float* __restrict__ P,
               const int* __restrict__ flags, void* __restrict__ outv) {
    __shared__ float zsrc[FC1N];
    __shared__ float z2s[FC2N];
    __shared__ float lg[OUTN];
    __shared__ float red[2];
    int b = blockIdx.x, t = threadIdx.x;
    #pragma unroll
    for (int r = 0; r < 4; ++r) zsrc[t + r * 128] = z1[b * FC1N + t + r * 128];
    __syncthreads();
    {
        int f = t;
        const float4* wr = (const float4*)(P + P_FW2 + (size_t)f * FC1N);
        const float4* zr = (const float4*)zsrc;
        float acc = P[P_FB2 + f];
        for (int k = 0; k < FC1N / 4; ++k) {
            float4 wv = wr[k];
            float4 zv = zr[k];
            acc += wv.x * zv.x + wv.y * zv.y + wv.z * zv.z + wv.w * zv.w;
        }
        float s = P[P_BF2G + f] / sqrtf(P[P_BF2V + f] + EPSV);
        acc = (acc - P[P_BF2M + f]) * s + P[P_BF2B + f];
        z2s[f] = fmaxf(acc, 0.f);
    }
    __syncthreads();
    if (t < OUTN) {
        float acc = P[P_FOB + t];
        const float* wr = P + P_FOW + t * FC2N;
        for (int k = 0; k < FC2N; ++k) acc += wr[k] * z2s[k];
        lg[t] = acc;
    }
    __syncthreads();
    if (t == 0) {
        float mx = lg[0];
        for (int o = 1; o < OUTN; ++o) mx = fmaxf(mx, lg[o]);
        float s = 0.f;
        for (int o = 0; o < OUTN; ++o) s += expf(lg[o] - mx);
        red[0] = mx; red[1] = s;
    }
    __syncthreads();
    if (t < OUTN) {
        float p = expf(lg[t] - red[0]) / red[1];
        if (flags[0]) {
            __hip_bfloat16* o = (__hip_bfloat16*)outv;
            o[b * OUTN + t] = __float2bfloat16(p);
            o[BB * OUTN + b * OUTN + t] = __float2bfloat16(lg[t]);
        } else {
            float* o = (float*)outv;
            o[b * OUTN + t] = p;
            o[BB * OUTN + b * OUTN + t] = lg[t];
        }
    }
}

// ---------------------------------------------------------------------------
extern "C" void kernel_launch(void* const* d_in, const int* in_sizes, int n_in,
                              void* d_out, int out_size, void* d_ws, size_t ws_size,
                              hipStream_t stream) {
    char* ws = (char*)d_ws;
    size_t o = 0;
    auto carve = [&](size_t bytes) { void* p = ws + o; o += (bytes + 255) & ~(size_t)255; return p; };
    int*   flags  = (int*)  carve(16);
    int*   ei32   = (int*)  carve((size_t)2 * EE * sizeof(int));
    // cnt + statsS + statsQ carved contiguously -> single memset zeroes all
    int*   cnt    = (int*)  carve(NN * sizeof(int));
    float* statsS = (float*)carve(BB * sizeof(float));
    float* statsQ = (float*)carve(BB * sizeof(float));
    int*   off    = (int*)  carve((NN + 1) * sizeof(int));
    int*   cursor = (int*)  carve(NN * sizeof(int));
    int*   rcsr   = (int*)  carve(EE * sizeof(int));
    float* wcsr   = (float*)carve(EE * sizeof(float));
    float* P      = (float*)carve((size_t)P_TOT * sizeof(float));
    float* hb     = (float*)carve((size_t)BB * HROW * sizeof(float));
    unsigned short* zT = (unsigned short*)carve((size_t)D0 * BB * sizeof(unsigned short));
    float* out1p  = (float*)carve((size_t)NKC * FC1N * BB * sizeof(float));
    float* z1     = (float*)carve(BB * FC1N * sizeof(float));

    size_t zero_bytes = ((NN * sizeof(int) + 255) & ~(size_t)255)
                      + 2 * ((BB * sizeof(float) + 255) & ~(size_t)255);
    hipMemsetAsync(cnt, 0, zero_bytes, stream);

    PTab tab;
    tab.p[0]  = d_in[2];   tab.p[1]  = d_in[4];   tab.p[2]  = d_in[5];
    tab.p[3]  = d_in[6];   tab.p[4]  = d_in[7];   tab.p[5]  = d_in[8];
    tab.p[6]  = d_in[9];   tab.p[7]  = d_in[10];  tab.p[8]  = d_in[11];
    tab.p[9]  = d_in[12];  tab.p[10] = d_in[13];  tab.p[11] = d_in[14];
    tab.p[12] = d_in[15];  tab.p[13] = d_in[16];  tab.p[14] = d_in[17];
    tab.p[15] = d_in[18];  tab.p[16] = d_in[19];  tab.p[17] = d_in[21];
    tab.p[18] = d_in[22];  tab.p[19] = d_in[23];  tab.p[20] = d_in[24];
    tab.p[21] = d_in[25];  tab.p[22] = d_in[26];  tab.p[23] = d_in[27];
    tab.p[24] = d_in[28];  tab.p[25] = d_in[29];  tab.p[26] = d_in[30];
    tab.p[27] = d_in[31];  tab.p[28] = d_in[32];  tab.p[29] = d_in[33];

    long long prep_tot = 2LL * EE + P_TOT;
    k_prep<<<(int)((prep_tot + 255) / 256), 256, 0, stream>>>(
        d_in[1], (const unsigned int*)d_in[2], tab, ei32, cnt, flags, P);

    k_scan   <<<1, 1024, 0, stream>>>(cnt, off, cursor);
    k_scatter<<<(EE + 255) / 256, 256, 0, stream>>>(ei32, P + P_EWRAW, cursor, rcsr, wcsr);
    k_agg_sage<<<NN / 4, 256, 0, stream>>>(d_in[0], flags, off, rcsr, wcsr,
                                           P + P_SW, P + P_SB, hb, statsS, statsQ);
    k_conv_stack<<<NN / 4, 256, 0, stream>>>(hb, statsS, statsQ, P, zT);
    dim3 g7(FC1N / 64, NKC);
    k_fc1    <<<g7, 256, 0, stream>>>(zT, d_in[20], flags, out1p);
    k_fc1_fin<<<(BB * FC1N + 255) / 256, 256, 0, stream>>>(out1p, P, z1);
    k_fc2head<<<BB, 128, 0, stream>>>(z1, P, flags, (void*)d_out);
}

// Round 13
// 260.446 us; speedup vs baseline: 2.7923x; 1.0315x over previous
//
#include <hip/hip_runtime.h>
#include <hip/hip_bf16.h>
#include <math.h>

// Problem constants
#define NN   3000
#define EE   96000
#define BB   64
#define CIN  8
#define MID  16
#define G1   32
#define G2   8
#define FC1N 512
#define FC2N 128
#define OUTN 10
#define EPSV 1e-5f

#define BC   (BB * CIN)          // 512
#define HROW (NN * MID)          // 48000 (logical; hb now stored [n][b*16+m])
#define D0   (G2 * NN)           // 24000

// fp32 param-pack offsets (elements)
#define P_EWRAW 0
#define P_SW    96000
#define P_SB    96128
#define P_LNG   96144
#define P_LNB   144144
#define P_C1W   192144
#define P_C1B   192656
#define P_BN1G  192688
#define P_BN1B  192720
#define P_BN1M  192752
#define P_BN1V  192784
#define P_C2W   192816
#define P_C2B   193072
#define P_BN2G  193080
#define P_BN2B  193088
#define P_BN2M  193096
#define P_BN2V  193104
#define P_FB1   193112
#define P_BF1G  193624
#define P_BF1B  194136
#define P_BF1M  194648
#define P_BF1V  195160
#define P_FW2   195672
#define P_FB2   261208
#define P_BF2G  261336
#define P_BF2B  261464
#define P_BF2M  261592
#define P_BF2V  261720
#define P_FOW   261848
#define P_FOB   263128
#define P_TOT   263138

// FC1 K-split: 24000 = 75 chunks x 320; each chunk = 10 MFMA K-steps of 32
#define KCH  320
#define NKC  75

__device__ __forceinline__ float b2f(unsigned short u) {
    union { unsigned int i; float f; } c;
    c.i = ((unsigned int)u) << 16;
    return c.f;
}
__device__ __forceinline__ unsigned short f2b_rne(float x) {
    union { float f; unsigned int u; } c; c.f = x;
    unsigned int r = c.u + 0x7FFFu + ((c.u >> 16) & 1u);
    return (unsigned short)(r >> 16);
}
__device__ __forceinline__ void acc_bf16x8(float* a, uint4 u, float w) {
    a[0] += b2f((unsigned short)(u.x & 0xFFFFu)) * w;
    a[1] += b2f((unsigned short)(u.x >> 16))     * w;
    a[2] += b2f((unsigned short)(u.y & 0xFFFFu)) * w;
    a[3] += b2f((unsigned short)(u.y >> 16))     * w;
    a[4] += b2f((unsigned short)(u.z & 0xFFFFu)) * w;
    a[5] += b2f((unsigned short)(u.z >> 16))     * w;
    a[6] += b2f((unsigned short)(u.w & 0xFFFFu)) * w;
    a[7] += b2f((unsigned short)(u.w >> 16))     * w;
}

typedef __attribute__((ext_vector_type(8))) short short8;
typedef __attribute__((ext_vector_type(4))) float f32x4;

// ---------------------------------------------------------------------------
// K_prep: fused dtype sniffs + edge_index convert + histogram + param cvt.
struct PTab { const void* p[30]; };
__global__ __launch_bounds__(256)
void k_prep(const void* __restrict__ ei_raw, const unsigned int* __restrict__ ewr,
            PTab tab,
            int* __restrict__ ei32, int* __restrict__ cnt, int* __restrict__ flags,
            float* __restrict__ P) {
    __shared__ int sh_is64, sh_bf;
    if (threadIdx.x == 0) {
        const int* pw = (const int*)ei_raw;
        int any = 0;
        #pragma unroll
        for (int i = 1; i < 32; i += 2) any |= pw[i];
        sh_is64 = (any == 0) ? 1 : 0;
        unsigned int w = ewr[0];
        sh_bf = ((w >> 16) == (w & 0xFFFFu)) ? 1 : 0;
        if (blockIdx.x == 0) flags[0] = sh_bf;
    }
    __syncthreads();
    int bf = sh_bf;
    long long gi = (long long)blockIdx.x * blockDim.x + threadIdx.x;
    if (gi < 2 * EE) {
        int i = (int)gi;
        int v = sh_is64 ? (int)((const long long*)ei_raw)[i]
                        : ((const int*)ei_raw)[i];
        ei32[i] = v;
        if (i >= EE) atomicAdd(&cnt[v], 1);   // col half
        return;
    }
    gi -= 2 * EE;
    if (gi >= P_TOT) return;
    int i = (int)gi;
    const int off[31] = {
        P_EWRAW, P_SW, P_SB, P_LNG, P_LNB, P_C1W, P_C1B, P_BN1G, P_BN1B, P_BN1M,
        P_BN1V, P_C2W, P_C2B, P_BN2G, P_BN2B, P_BN2M, P_BN2V, P_FB1, P_BF1G,
        P_BF1B, P_BF1M, P_BF1V, P_FW2, P_FB2, P_BF2G, P_BF2B, P_BF2M, P_BF2V,
        P_FOW, P_FOB, P_TOT };
    int r = 0;
    #pragma unroll
    for (int j = 1; j < 31; ++j) r += (i >= off[j]) ? 1 : 0;
    int e = i - off[r];
    P[i] = bf ? b2f(((const unsigned short*)tab.p[r])[e])
              : ((const float*)tab.p[r])[e];
}

// K2: single-block exclusive scan over N=3000 counts
__global__ void k_scan(const int* __restrict__ cnt, int* __restrict__ off,
                       int* __restrict__ cursor) {
    __shared__ int part[1024];
    int t = threadIdx.x;
    int base = t * 3;
    int c0 = 0, c1 = 0, c2 = 0;
    if (base     < NN) c0 = cnt[base];
    if (base + 1 < NN) c1 = cnt[base + 1];
    if (base + 2 < NN) c2 = cnt[base + 2];
    int s = c0 + c1 + c2;
    part[t] = s;
    __syncthreads();
    for (int d = 1; d < 1024; d <<= 1) {
        int v = (t >= d) ? part[t - d] : 0;
        __syncthreads();
        part[t] += v;
        __syncthreads();
    }
    int excl = part[t] - s;
    if (base < NN)     { off[base]     = excl;           cursor[base]     = excl; }
    if (base + 1 < NN) { off[base + 1] = excl + c0;      cursor[base + 1] = excl + c0; }
    if (base + 2 < NN) { off[base + 2] = excl + c0 + c1; cursor[base + 2] = excl + c0 + c1; }
    if (t == 1023) off[NN] = part[1023];
}

// K3: scatter (row, sigmoid(w)) into CSR order
__global__ void k_scatter(const int* __restrict__ ei, const float* __restrict__ ew,
                          int* __restrict__ cursor,
                          int* __restrict__ rcsr, float* __restrict__ wcsr) {
    int e = blockIdx.x * blockDim.x + threadIdx.x;
    if (e < EE) {
        int p = atomicAdd(&cursor[ei[EE + e]], 1);
        rcsr[p] = ei[e];
        wcsr[p] = 1.f / (1.f + expf(-ew[e]));
    }
}

// K4 (R12 redesign): WAVE-PER-NODE agg + in-lane SAGE + ReLU + fused LN sums.
// lane = batch b; per edge ONE uint4 load covers the whole 1 KB bf16 x-row
// (vs 4 wave-loads before). Lane l holds x[row][b=l][c=0..7] -> SAGE matmul
// entirely in-lane (no LDS, no syncthreads in edge loop). 750 blocks x 4
// independent waves = 3000 node-waves (R9's TLP restored). hb stored
// [n][b*16+m]: wave stores 4 KB contiguous, conv_stack reads contiguous.
__global__ __launch_bounds__(256)
void k_agg_sage(const void* __restrict__ xraw, const int* __restrict__ flags,
                const int* __restrict__ off,
                const int* __restrict__ rcsr, const float* __restrict__ wcsr,
                const float* __restrict__ sw, const float* __restrict__ sb,
                float* __restrict__ hb2,
                float* __restrict__ statsS, float* __restrict__ statsQ) {
    __shared__ float swL[CIN * MID];
    __shared__ float sbL[MID];
    __shared__ float lnS[BB], lnQ[BB];
    int t = threadIdx.x;
    if (t < CIN * MID) swL[t] = sw[t];
    if (t < MID)       sbL[t] = sb[t];
    if (t < BB) { lnS[t] = 0.f; lnQ[t] = 0.f; }
    __syncthreads();
    int wv = t >> 6, lane = t & 63;
    int n = blockIdx.x * 4 + wv;
    int k0 = off[n], k1 = off[n + 1];
    float a[8];
    #pragma unroll
    for (int c = 0; c < 8; ++c) a[c] = 0.f;
    int k = k0;
    if (flags[0]) {
        const uint4* xu = (const uint4*)xraw;     // bf16 row = 64 uint4
        for (; k + 3 < k1; k += 4) {              // 4 x 16B loads in flight
            int   r0 = rcsr[k],     r1 = rcsr[k + 1];
            int   r2 = rcsr[k + 2], r3 = rcsr[k + 3];
            float w0 = wcsr[k],     w1 = wcsr[k + 1];
            float w2 = wcsr[k + 2], w3 = wcsr[k + 3];
            uint4 u0 = xu[(size_t)r0 * 64 + lane];
            uint4 u1 = xu[(size_t)r1 * 64 + lane];
            uint4 u2 = xu[(size_t)r2 * 64 + lane];
            uint4 u3 = xu[(size_t)r3 * 64 + lane];
            acc_bf16x8(a, u0, w0);
            acc_bf16x8(a, u1, w1);
            acc_bf16x8(a, u2, w2);
            acc_bf16x8(a, u3, w3);
        }
        for (; k < k1; ++k) {
            uint4 u0 = xu[(size_t)rcsr[k] * 64 + lane];
            acc_bf16x8(a, u0, wcsr[k]);
        }
    } else {
        const float4* xf = (const float4*)xraw;   // fp32 row = 128 float4
        for (; k + 1 < k1; k += 2) {              // 4 x 16B loads in flight
            int   r0 = rcsr[k],   r1 = rcsr[k + 1];
            float w0 = wcsr[k],   w1 = wcsr[k + 1];
            float4 f0 = xf[(size_t)r0 * 128 + lane * 2];
            float4 f1 = xf[(size_t)r0 * 128 + lane * 2 + 1];
            float4 g0 = xf[(size_t)r1 * 128 + lane * 2];
            float4 g1 = xf[(size_t)r1 * 128 + lane * 2 + 1];
            a[0] += f0.x * w0 + g0.x * w1;  a[1] += f0.y * w0 + g0.y * w1;
            a[2] += f0.z * w0 + g0.z * w1;  a[3] += f0.w * w0 + g0.w * w1;
            a[4] += f1.x * w0 + g1.x * w1;  a[5] += f1.y * w0 + g1.y * w1;
            a[6] += f1.z * w0 + g1.z * w1;  a[7] += f1.w * w0 + g1.w * w1;
        }
        if (k < k1) {
            float w0 = wcsr[k];
            float4 f0 = xf[(size_t)rcsr[k] * 128 + lane * 2];
            float4 f1 = xf[(size_t)rcsr[k] * 128 + lane * 2 + 1];
            a[0] += f0.x * w0;  a[1] += f0.y * w0;
            a[2] += f0.z * w0;  a[3] += f0.w * w0;
            a[4] += f1.x * w0;  a[5] += f1.y * w0;
            a[6] += f1.z * w0;  a[7] += f1.w * w0;
        }
    }
    float inv = 1.f / fmaxf((float)(k1 - k0), 1.f);
    #pragma unroll
    for (int c = 0; c < 8; ++c) a[c] *= inv;
    // in-lane SAGE matmul (b = lane) + ReLU + LN partial sums
    float accS = 0.f, accQ = 0.f;
    float ov[MID];
    #pragma unroll
    for (int m = 0; m < MID; ++m) {
        float v = sbL[m];
        #pragma unroll
        for (int c = 0; c < CIN; ++c) v += a[c] * swL[c * MID + m];
        v = fmaxf(v, 0.f);
        ov[m] = v;
        accS += v;
        accQ += v * v;
    }
    float* hp = hb2 + (size_t)n * 1024 + lane * 16;   // wave = 4 KB contiguous
    #pragma unroll
    for (int m4 = 0; m4 < 4; ++m4)
        *(float4*)(hp + m4 * 4) = make_float4(ov[m4*4], ov[m4*4+1], ov[m4*4+2], ov[m4*4+3]);
    // LN reduce: lane=b; 4 waves -> LDS atomics, then 64 global atomics/block
    atomicAdd(&lnS[lane], accS);
    atomicAdd(&lnQ[lane], accQ);
    __syncthreads();
    if (t < BB) {
        atomicAdd(&statsS[t], lnS[t]);
        atomicAdd(&statsQ[t], lnQ[t]);
    }
}

// K6: LN apply + conv1(+relu+bn1) + conv2(+relu+bn2) -> zT (packed bf16).
// Reads hb2[n][b*16+m] (contiguous 4 KB per node).
__global__ __launch_bounds__(256)
void k_conv_stack(const float* __restrict__ hb2,
                  const float* __restrict__ statsS, const float* __restrict__ statsQ,
                  const float* __restrict__ P, unsigned short* __restrict__ zT) {
    __shared__ float hbt[64 * 65];
    __shared__ float w1s[G1 * MID], w2s[G2 * G1];
    __shared__ float c1s[G1], s1[G1], t1[G1];
    __shared__ float c2s[G2], s2[G2], t2[G2];
    int t = threadIdx.x;
    int n0 = blockIdx.x * 4;
    for (int j = t; j < G1 * MID; j += 256) w1s[j] = P[P_C1W + j];  // 512 > 256
    if (t < G2 * G1)  w2s[t] = P[P_C2W + t];
    if (t < G1) {
        float s = P[P_BN1G + t] / sqrtf(P[P_BN1V + t] + EPSV);
        c1s[t] = P[P_C1B + t]; s1[t] = s; t1[t] = P[P_BN1B + t] - P[P_BN1M + t] * s;
    }
    if (t < G2) {
        float s = P[P_BN2G + t] / sqrtf(P[P_BN2V + t] + EPSV);
        c2s[t] = P[P_C2B + t]; s2[t] = s; t2[t] = P[P_BN2B + t] - P[P_BN2M + t] * s;
    }
    // contiguous load: 4 nodes x 1024 floats; hbt[b*65 + nsub*16 + m]
    #pragma unroll
    for (int r = 0; r < 4; ++r) {
        int j = t;                     // within-node float4 id (256)
        float4 v = *(const float4*)(hb2 + (size_t)(n0 + r) * 1024 + j * 4);
        int b = j >> 2, m4 = j & 3;
        int ld = b * 65 + r * 16 + m4 * 4;
        hbt[ld] = v.x; hbt[ld + 1] = v.y; hbt[ld + 2] = v.z; hbt[ld + 3] = v.w;
    }
    __syncthreads();
    int nl = t >> 6, b = t & 63;
    int n = n0 + nl;
    float mu = statsS[b] / (float)HROW;
    float var = statsQ[b] / (float)HROW - mu * mu;
    float rs = 1.f / sqrtf(var + EPSV);
    float tv[MID];
    #pragma unroll
    for (int m = 0; m < MID; ++m) {
        float g = P[P_LNG + n * MID + m], lb = P[P_LNB + n * MID + m];
        tv[m] = (hbt[b * 65 + nl * 16 + m] - mu) * rs * g + lb;
    }
    float v1[G1];
    #pragma unroll
    for (int o = 0; o < G1; ++o) {
        float d = c1s[o];
        #pragma unroll
        for (int m = 0; m < MID; ++m) d += w1s[o * MID + m] * tv[m];
        d = fmaxf(d, 0.f);
        v1[o] = d * s1[o] + t1[o];
    }
    #pragma unroll
    for (int o2 = 0; o2 < G2; ++o2) {
        float d = c2s[o2];
        #pragma unroll
        for (int c = 0; c < G1; ++c) d += w2s[o2 * G1 + c] * v1[c];
        d = fmaxf(d, 0.f);
        zT[((size_t)(o2 * NN + n)) * BB + b] = f2b_rne(d * s2[o2] + t2[o2]);
    }
}

// K7: FC1 partial GEMM via MFMA bf16 (R8 design, best measured).
__global__ __launch_bounds__(256)
void k_fc1(const unsigned short* __restrict__ zT, const void* __restrict__ w1raw,
           const int* __restrict__ flags, float* __restrict__ out1p) {
    __shared__ unsigned int zs[64 * 20];   // [b][k-pair], row = 20 u32 = 80 B
    int kc = blockIdx.y;
    int t = threadIdx.x;
    int lane = t & 63;
    int wv = t >> 6;
    int n = lane & 15;           // f-row in A, b-col in B/D
    int q = lane >> 4;           // quad
    int fbase = blockIdx.x * 64 + wv * 16;
    int bf = flags[0];
    const size_t kcb = (size_t)kc * KCH;
    const float*          w1f = (const float*)w1raw;
    const unsigned short* w1b = (const unsigned short*)w1raw;

    f32x4 acc0 = {0.f, 0.f, 0.f, 0.f};
    f32x4 acc1 = {0.f, 0.f, 0.f, 0.f};
    f32x4 acc2 = {0.f, 0.f, 0.f, 0.f};
    f32x4 acc3 = {0.f, 0.f, 0.f, 0.f};

    int zb = t & 63;
    int kg = t >> 6;

    for (int ks = 0; ks < KCH / 32; ++ks) {
        size_t k0 = kcb + (size_t)ks * 32;
        const unsigned short* zsrc = zT + (k0 + kg * 8) * BB + zb;
        unsigned short zv[8];
        #pragma unroll
        for (int j = 0; j < 8; ++j) zv[j] = zsrc[j * BB];
        unsigned int pk0 = (unsigned int)zv[0] | ((unsigned int)zv[1] << 16);
        unsigned int pk1 = (unsigned int)zv[2] | ((unsigned int)zv[3] << 16);
        unsigned int pk2 = (unsigned int)zv[4] | ((unsigned int)zv[5] << 16);
        unsigned int pk3 = (unsigned int)zv[6] | ((unsigned int)zv[7] << 16);
        __syncthreads();
        *(uint4*)&zs[zb * 20 + kg * 4] = make_uint4(pk0, pk1, pk2, pk3);
        short8 av;
        if (bf) {
            av = *(const short8*)(w1b + (size_t)(fbase + n) * D0 + k0 + q * 8);
        } else {
            const float* wr = w1f + (size_t)(fbase + n) * D0 + k0 + q * 8;
            float4 wa = *(const float4*)wr;
            float4 wb = *(const float4*)(wr + 4);
            av[0] = (short)f2b_rne(wa.x); av[1] = (short)f2b_rne(wa.y);
            av[2] = (short)f2b_rne(wa.z); av[3] = (short)f2b_rne(wa.w);
            av[4] = (short)f2b_rne(wb.x); av[5] = (short)f2b_rne(wb.y);
            av[6] = (short)f2b_rne(wb.z); av[7] = (short)f2b_rne(wb.w);
        }
        __syncthreads();
        const char* zbase = (const char*)zs + q * 16;
        short8 bv0 = *(const short8*)(zbase + (0  + n) * 80);
        short8 bv1 = *(const short8*)(zbase + (16 + n) * 80);
        short8 bv2 = *(const short8*)(zbase + (32 + n) * 80);
        short8 bv3 = *(const short8*)(zbase + (48 + n) * 80);
        acc0 = __builtin_amdgcn_mfma_f32_16x16x32_bf16(av, bv0, acc0, 0, 0, 0);
        acc1 = __builtin_amdgcn_mfma_f32_16x16x32_bf16(av, bv1, acc1, 0, 0, 0);
        acc2 = __builtin_amdgcn_mfma_f32_16x16x32_bf16(av, bv2, acc2, 0, 0, 0);
        acc3 = __builtin_amdgcn_mfma_f32_16x16x32_bf16(av, bv3, acc3, 0, 0, 0);
    }
    float* op = out1p + ((size_t)kc * FC1N + fbase + q * 4) * BB + n;
    #pragma unroll
    for (int r = 0; r < 4; ++r) {
        op[r * BB +  0] = acc0[r];
        op[r * BB + 16] = acc1[r];
        op[r * BB + 32] = acc2[r];
        op[r * BB + 48] = acc3[r];
    }
}

// K8: FC1 reduce partials + bias + bn + relu
__global__ void k_fc1_fin(const float* __restrict__ out1p, const float* __restrict__ P,
                          float* __restrict__ z1) {
    int i = blockIdx.x * blockDim.x + threadIdx.x;
    if (i < BB * FC1N) {
        int f = i >> 6, b = i & 63;
        float acc = 0.f;
        for (int kc = 0; kc < NKC; ++kc)
            acc += out1p[((size_t)kc * FC1N + f) * BB + b];
        acc += P[P_FB1 + f];
        float s = P[P_BF1G + f] / sqrtf(P[P_BF1V + f] + EPSV);
        acc = (acc - P[P_BF1M + f]) * s + P[P_BF1B + f];
        z1[b * FC1N + f] = fmaxf(acc, 0.f);
    }
}

// K9: fused FC2(+bn+relu) + head + softmax; one block per batch element.
__global__ __launch_bounds__(128)
void k_fc2head(const float* __restrict__ z1, const float* __restrict__ P,
               const int* __restrict__ flags, void* __restrict__ outv) {
    __shared__ float zsrc[FC1N];
    __shared__ float z2s[FC2N];
    __shared__ float lg[OUTN];
    __shared__ float red[2];
    int b = blockIdx.x, t = threadIdx.x;
    #pragma unroll
    for (int r = 0; r < 4; ++r) zsrc[t + r * 128] = z1[b * FC1N + t + r * 128];
    __syncthreads();
    {
        int f = t;
        const float4* wr = (const float4*)(P + P_FW2 + (size_t)f * FC1N);
        const float4* zr = (const float4*)zsrc;
        float acc = P[P_FB2 + f];
        for (int k = 0; k < FC1N / 4; ++k) {
            float4 wv = wr[k];
            float4 zv = zr[k];
            acc += wv.x * zv.x + wv.y * zv.y + wv.z * zv.z + wv.w * zv.w;
        }
        float s = P[P_BF2G + f] / sqrtf(P[P_BF2V + f] + EPSV);
        acc = (acc - P[P_BF2M + f]) * s + P[P_BF2B + f];
        z2s[f] = fmaxf(acc, 0.f);
    }
    __syncthreads();
    if (t < OUTN) {
        float acc = P[P_FOB + t];
        const float* wr = P + P_FOW + t * FC2N;
        for (int k = 0; k < FC2N; ++k) acc += wr[k] * z2s[k];
        lg[t] = acc;
    }
    __syncthreads();
    if (t == 0) {
        float mx = lg[0];
        for (int o = 1; o < OUTN; ++o) mx = fmaxf(mx, lg[o]);
        float s = 0.f;
        for (int o = 0; o < OUTN; ++o) s += expf(lg[o] - mx);
        red[0] = mx; red[1] = s;
    }
    __syncthreads();
    if (t < OUTN) {
        float p = expf(lg[t] - red[0]) / red[1];
        if (flags[0]) {
            __hip_bfloat16* o = (__hip_bfloat16*)outv;
            o[b * OUTN + t] = __float2bfloat16(p);
            o[BB * OUTN + b * OUTN + t] = __float2bfloat16(lg[t]);
        } else {
            float* o = (float*)outv;
            o[b * OUTN + t] = p;
            o[BB * OUTN + b * OUTN + t] = lg[t];
        }
    }
}

// ---------------------------------------------------------------------------
extern "C" void kernel_launch(void* const* d_in, const int* in_sizes, int n_in,
                              void* d_out, int out_size, void* d_ws, size_t ws_size,
                              hipStream_t stream) {
    char* ws = (char*)d_ws;
    size_t o = 0;
    auto carve = [&](size_t bytes) { void* p = ws + o; o += (bytes + 255) & ~(size_t)255; return p; };
    int*   flags  = (int*)  carve(16);
    int*   ei32   = (int*)  carve((size_t)2 * EE * sizeof(int));
    // cnt + statsS + statsQ carved contiguously -> single memset zeroes all
    int*   cnt    = (int*)  carve(NN * sizeof(int));
    float* statsS = (float*)carve(BB * sizeof(float));
    float* statsQ = (float*)carve(BB * sizeof(float));
    int*   off    = (int*)  carve((NN + 1) * sizeof(int));
    int*   cursor = (int*)  carve(NN * sizeof(int));
    int*   rcsr   = (int*)  carve(EE * sizeof(int));
    float* wcsr   = (float*)carve(EE * sizeof(float));
    float* P      = (float*)carve((size_t)P_TOT * sizeof(float));
    float* hb2    = (float*)carve((size_t)NN * 1024 * sizeof(float));
    unsigned short* zT = (unsigned short*)carve((size_t)D0 * BB * sizeof(unsigned short));
    float* out1p  = (float*)carve((size_t)NKC * FC1N * BB * sizeof(float));
    float* z1     = (float*)carve(BB * FC1N * sizeof(float));

    size_t zero_bytes = ((NN * sizeof(int) + 255) & ~(size_t)255)
                      + 2 * ((BB * sizeof(float) + 255) & ~(size_t)255);
    hipMemsetAsync(cnt, 0, zero_bytes, stream);

    PTab tab;
    tab.p[0]  = d_in[2];   tab.p[1]  = d_in[4];   tab.p[2]  = d_in[5];
    tab.p[3]  = d_in[6];   tab.p[4]  = d_in[7];   tab.p[5]  = d_in[8];
    tab.p[6]  = d_in[9];   tab.p[7]  = d_in[10];  tab.p[8]  = d_in[11];
    tab.p[9]  = d_in[12];  tab.p[10] = d_in[13];  tab.p[11] = d_in[14];
    tab.p[12] = d_in[15];  tab.p[13] = d_in[16];  tab.p[14] = d_in[17];
    tab.p[15] = d_in[18];  tab.p[16] = d_in[19];  tab.p[17] = d_in[21];
    tab.p[18] = d_in[22];  tab.p[19] = d_in[23];  tab.p[20] = d_in[24];
    tab.p[21] = d_in[25];  tab.p[22] = d_in[26];  tab.p[23] = d_in[27];
    tab.p[24] = d_in[28];  tab.p[25] = d_in[29];  tab.p[26] = d_in[30];
    tab.p[27] = d_in[31];  tab.p[28] = d_in[32];  tab.p[29] = d_in[33];

    long long prep_tot = 2LL * EE + P_TOT;
    k_prep<<<(int)((prep_tot + 255) / 256), 256, 0, stream>>>(
        d_in[1], (const unsigned int*)d_in[2], tab, ei32, cnt, flags, P);

    k_scan   <<<1, 1024, 0, stream>>>(cnt, off, cursor);
    k_scatter<<<(EE + 255) / 256, 256, 0, stream>>>(ei32, P + P_EWRAW, cursor, rcsr, wcsr);
    k_agg_sage<<<NN / 4, 256, 0, stream>>>(d_in[0], flags, off, rcsr, wcsr,
                                           P + P_SW, P + P_SB, hb2, statsS, statsQ);
    k_conv_stack<<<NN / 4, 256, 0, stream>>>(hb2, statsS, statsQ, P, zT);
    dim3 g7(FC1N / 64, NKC);
    k_fc1    <<<g7, 256, 0, stream>>>(zT, d_in[20], flags, out1p);
    k_fc1_fin<<<(BB * FC1N + 255) / 256, 256, 0, stream>>>(out1p, P, z1);
    k_fc2head<<<BB, 128, 0, stream>>>(z1, P, flags, (void*)d_out);
}